// Round 6
// baseline (2016.232 us; speedup 1.0000x reference)
//
#include <hip/hip_runtime.h>
#include <math.h>

#define TSEQ 2048
#define EMB  1024
#define NH   16
#define HD   64
#define NB   2
#define L2E  1.4426950408889634f

#if defined(__has_builtin)
#if __has_builtin(__builtin_amdgcn_exp2f)
#define EXP2(x) __builtin_amdgcn_exp2f(x)
#else
#define EXP2(x) exp2f(x)
#endif
#else
#define EXP2(x) exp2f(x)
#endif

// ---------------------------------------------------------------------------
// GEMM NT: C[i,j] = sum_k A[i,k] * B[j,k] + bias[j]
// A: M x K row-major, B: N x K row-major.
// mode 0: C0[i*N + j] = val   (plain row-major output)
// mode 1: qkv scatter into C0=q, C1=k, C2=v with layout [B,H,T,hd];
//         q pre-scaled by 0.125 (exact).
// Tile: 128x128 per block (256 threads), 8x8 per thread as 2x2 quadrants of
// 4x4 (quadrant offsets +0/+64 keep LDS reads at <=2-way bank conflicts).
// BK=16. LDS 2x 16x132 floats (~17 KB).
// ---------------------------------------------------------------------------
__global__ __launch_bounds__(256) void gemm_nt_kernel(
    const float* __restrict__ A, const float* __restrict__ B,
    const float* __restrict__ bias,
    float* __restrict__ C0, float* __restrict__ C1, float* __restrict__ C2,
    int M, int N, int K, int mode)
{
    __shared__ float As[16][132];   // [k][row], pad to 132 floats
    __shared__ float Bs[16][132];

    const int tid = threadIdx.x;
    const int i0 = blockIdx.x * 128;
    const int j0 = blockIdx.y * 128;
    const int ty = tid >> 4;         // 0..15
    const int tx = tid & 15;         // 0..15
    const int lr = tid >> 2;         // 0..63 staging row
    const int lc = (tid & 3) << 2;   // 0,4,8,12 staging k-offset

    const float* Ap0 = A + (size_t)(i0 + lr) * K + lc;
    const float* Ap1 = A + (size_t)(i0 + 64 + lr) * K + lc;
    const float* Bp0 = B + (size_t)(j0 + lr) * K + lc;
    const float* Bp1 = B + (size_t)(j0 + 64 + lr) * K + lc;

    float acc[2][2][4][4] = {};      // [ri][ci][r][c]

    for (int k0 = 0; k0 < K; k0 += 16) {
        float4 a0 = *(const float4*)(Ap0 + k0);
        float4 a1 = *(const float4*)(Ap1 + k0);
        float4 b0 = *(const float4*)(Bp0 + k0);
        float4 b1 = *(const float4*)(Bp1 + k0);
        As[lc+0][lr] = a0.x; As[lc+1][lr] = a0.y; As[lc+2][lr] = a0.z; As[lc+3][lr] = a0.w;
        As[lc+0][64+lr] = a1.x; As[lc+1][64+lr] = a1.y; As[lc+2][64+lr] = a1.z; As[lc+3][64+lr] = a1.w;
        Bs[lc+0][lr] = b0.x; Bs[lc+1][lr] = b0.y; Bs[lc+2][lr] = b0.z; Bs[lc+3][lr] = b0.w;
        Bs[lc+0][64+lr] = b1.x; Bs[lc+1][64+lr] = b1.y; Bs[lc+2][64+lr] = b1.z; Bs[lc+3][64+lr] = b1.w;
        __syncthreads();
        #pragma unroll
        for (int kk = 0; kk < 16; ++kk) {
            float4 av0 = *(const float4*)&As[kk][ty << 2];
            float4 av1 = *(const float4*)&As[kk][64 + (ty << 2)];
            float4 bv0 = *(const float4*)&Bs[kk][tx << 2];
            float4 bv1 = *(const float4*)&Bs[kk][64 + (tx << 2)];
            float ar[2][4] = {{av0.x, av0.y, av0.z, av0.w}, {av1.x, av1.y, av1.z, av1.w}};
            float br[2][4] = {{bv0.x, bv0.y, bv0.z, bv0.w}, {bv1.x, bv1.y, bv1.z, bv1.w}};
            #pragma unroll
            for (int ri = 0; ri < 2; ++ri)
                #pragma unroll
                for (int ci = 0; ci < 2; ++ci)
                    #pragma unroll
                    for (int r = 0; r < 4; ++r)
                        #pragma unroll
                        for (int c = 0; c < 4; ++c)
                            acc[ri][ci][r][c] = fmaf(ar[ri][r], br[ci][c], acc[ri][ci][r][c]);
        }
        __syncthreads();
    }

    float4 bias4[2];
    bias4[0] = *(const float4*)&bias[j0 + (tx << 2)];
    bias4[1] = *(const float4*)&bias[j0 + 64 + (tx << 2)];

    #pragma unroll
    for (int ri = 0; ri < 2; ++ri) {
        #pragma unroll
        for (int r = 0; r < 4; ++r) {
            const int i = i0 + ri * 64 + (ty << 2) + r;
            #pragma unroll
            for (int ci = 0; ci < 2; ++ci) {
                float4 val;
                val.x = acc[ri][ci][r][0] + bias4[ci].x;
                val.y = acc[ri][ci][r][1] + bias4[ci].y;
                val.z = acc[ri][ci][r][2] + bias4[ci].z;
                val.w = acc[ri][ci][r][3] + bias4[ci].w;
                const int j = j0 + ci * 64 + (tx << 2);
                if (mode == 0) {
                    *(float4*)&C0[(size_t)i * N + j] = val;
                } else {
                    const int which = j >> 10;          // 4 cols stay in one 64-block
                    const int e = j & (EMB - 1);
                    const int h = e >> 6, d = e & (HD - 1);
                    const int b = i >> 11, t = i & (TSEQ - 1);
                    float* dst = (which == 0) ? C0 : (which == 1 ? C1 : C2);
                    if (which == 0) { val.x *= 0.125f; val.y *= 0.125f; val.z *= 0.125f; val.w *= 0.125f; }
                    *(float4*)&dst[(size_t)((b * NH + h) * TSEQ + t) * HD + d] = val;
                }
            }
        }
    }
}

// ---------------------------------------------------------------------------
// In-place rotary on k.
// ---------------------------------------------------------------------------
__global__ __launch_bounds__(256) void rotary_k_kernel(
    float* __restrict__ k,
    const float* __restrict__ mre, const float* __restrict__ mim)
{
    const int idx = blockIdx.x * 256 + threadIdx.x;   // 0 .. 2^21-1 pairs
    const int d2 = idx & 31;
    const int t  = (idx >> 5) & (TSEQ - 1);
    const int b  = idx >> 20;
    float2 kv = *(float2*)(k + ((size_t)idx << 1));
    const int mix = (b * TSEQ + t) * 32 + d2;
    const float mr = mre[mix], mi = mim[mix];
    float2 out;
    out.x = kv.x * mr - kv.y * mi;
    out.y = kv.x * mi + kv.y * mr;
    *(float2*)(k + ((size_t)idx << 1)) = out;
}

// ---------------------------------------------------------------------------
// Flash-style attention, 8 threads per q row (8 head-dims each).
// Block = 256 threads = 32 q rows; grid = 64 q-tiles x 32 (b,h) = 2048 blocks
// -> 8 blocks/CU = 32 waves/CU (100% theoretical occupancy; VGPR ~48, LDS 8.7KB).
// Scores via 3x __shfl_xor (1,2,4) within aligned 8-lane groups; (m,l) kept
// redundantly in all 8 lanes of a group. K/V tiles of 16 keys in LDS.
// ---------------------------------------------------------------------------
__global__ __launch_bounds__(256) void flash_attn_kernel(
    const float* __restrict__ q, const float* __restrict__ k,
    const float* __restrict__ v, const float* __restrict__ pad,
    float* __restrict__ o_tmp, float* __restrict__ m_out,
    float* __restrict__ linv_out)
{
    __shared__ float Ks[16][64];
    __shared__ float Vs[16][64];
    __shared__ float padv[16];

    const int tid  = threadIdx.x;
    const int bh   = blockIdx.x >> 6;                 // 0..31
    const int qt   = blockIdx.x & 63;                 // q tile of 32 rows
    const int row  = tid >> 3;                        // 0..31
    const int part = tid & 7;                         // 8-dim slice
    const int t    = (qt << 5) + row;
    const int b    = bh >> 4, h = bh & (NH - 1);

    // q slice: dims [part*8, part*8+8)
    const float* qp = q + ((size_t)bh * TSEQ + t) * HD + (part << 3);
    float qr[8];
    {
        float4 v0 = *(const float4*)(qp);
        float4 v1 = *(const float4*)(qp + 4);
        qr[0]=v0.x; qr[1]=v0.y; qr[2]=v0.z; qr[3]=v0.w;
        qr[4]=v1.x; qr[5]=v1.y; qr[6]=v1.z; qr[7]=v1.w;
    }
    float O[8];
    #pragma unroll
    for (int i = 0; i < 8; ++i) O[i] = 0.f;
    float m = -1e30f, l = 0.f;

    const int lrow = tid >> 4;          // 0..15
    const int lcol = (tid & 15) << 2;   // 0..60
    const float* kbase = k + (size_t)bh * TSEQ * HD;
    const float* vbase = v + (size_t)bh * TSEQ * HD;

    for (int k0 = 0; k0 < TSEQ; k0 += 16) {
        *(float4*)&Ks[lrow][lcol] = *(const float4*)(kbase + (size_t)(k0 + lrow) * HD + lcol);
        *(float4*)&Vs[lrow][lcol] = *(const float4*)(vbase + (size_t)(k0 + lrow) * HD + lcol);
        if (tid < 16) padv[tid] = pad[b * TSEQ + k0 + tid];
        __syncthreads();

        float sj[16];
        #pragma unroll
        for (int j = 0; j < 16; ++j) {
            float4 k0v = *(const float4*)&Ks[j][part << 3];
            float4 k1v = *(const float4*)&Ks[j][(part << 3) + 4];
            float a0 = qr[0] * k0v.x;
            float a1 = qr[1] * k0v.y;
            a0 = fmaf(qr[2], k0v.z, a0);
            a1 = fmaf(qr[3], k0v.w, a1);
            a0 = fmaf(qr[4], k1v.x, a0);
            a1 = fmaf(qr[5], k1v.y, a1);
            a0 = fmaf(qr[6], k1v.z, a0);
            a1 = fmaf(qr[7], k1v.w, a1);
            float partial = a0 + a1;
            partial += __shfl_xor(partial, 1);
            partial += __shfl_xor(partial, 2);
            partial += __shfl_xor(partial, 4);
            sj[j] = partial + padv[j];
        }

        float tmax = sj[0];
        #pragma unroll
        for (int j = 1; j < 16; ++j) tmax = fmaxf(tmax, sj[j]);
        const float mn = fmaxf(m, tmax);
        const float c = EXP2((m - mn) * L2E);
        l *= c;
        #pragma unroll
        for (int d = 0; d < 8; ++d) O[d] *= c;
        #pragma unroll
        for (int j = 0; j < 16; ++j) {
            const float p = EXP2((sj[j] - mn) * L2E);
            l += p;
            float4 v0 = *(const float4*)&Vs[j][part << 3];
            float4 v1 = *(const float4*)&Vs[j][(part << 3) + 4];
            O[0] = fmaf(p, v0.x, O[0]);
            O[1] = fmaf(p, v0.y, O[1]);
            O[2] = fmaf(p, v0.z, O[2]);
            O[3] = fmaf(p, v0.w, O[3]);
            O[4] = fmaf(p, v1.x, O[4]);
            O[5] = fmaf(p, v1.y, O[5]);
            O[6] = fmaf(p, v1.z, O[6]);
            O[7] = fmaf(p, v1.w, O[7]);
        }
        m = mn;
        __syncthreads();
    }

    const float inv = 1.f / l;
    float* op = o_tmp + ((size_t)(b * TSEQ + t)) * EMB + h * HD + (part << 3);
    float4 st0, st1;
    st0.x = O[0]*inv; st0.y = O[1]*inv; st0.z = O[2]*inv; st0.w = O[3]*inv;
    st1.x = O[4]*inv; st1.y = O[5]*inv; st1.z = O[6]*inv; st1.w = O[7]*inv;
    *(float4*)(op) = st0;
    *(float4*)(op + 4) = st1;
    if (part == 0) {
        m_out[bh * TSEQ + t] = m;
        linv_out[bh * TSEQ + t] = inv;
    }
}

// ---------------------------------------------------------------------------
// a_avg[b,q,kk] = (1/H) * sum_h exp(s_hqk - m[h,q]) * linv[h,q]
// ---------------------------------------------------------------------------
__global__ __launch_bounds__(256) void attn_avg_kernel(
    const float* __restrict__ q, const float* __restrict__ k,
    const float* __restrict__ pad, const float* __restrict__ m_arr,
    const float* __restrict__ linv_arr, float* __restrict__ a_avg)
{
    __shared__ float qT[64][36];    // [d][qi], pad 4
    __shared__ float kT[64][132];   // [d][kj], pad 4
    __shared__ float m_s[32], li_s[32];
    __shared__ float padv[128];

    const int tid = threadIdx.x;
    const int b  = blockIdx.z;
    const int q0 = blockIdx.y << 5;   // *32
    const int k0 = blockIdx.x << 7;   // *128
    const int tx = tid & 31;          // k sub
    const int ty = tid >> 5;          // 0..7 q sub

    if (tid < 128) padv[tid] = pad[b * TSEQ + k0 + tid];

    float sum[4][4];
    #pragma unroll
    for (int r = 0; r < 4; ++r)
        #pragma unroll
        for (int c = 0; c < 4; ++c) sum[r][c] = 0.f;

    for (int h = 0; h < NH; ++h) {
        __syncthreads();   // protect previous iteration's reads
        const size_t base = (size_t)(b * NH + h) * TSEQ;
        #pragma unroll
        for (int it = 0; it < 2; ++it) {
            const int ff = tid + (it << 8);
            const int row = ff >> 4, c4 = (ff & 15) << 2;
            float4 v4 = *(const float4*)&q[(base + q0 + row) * HD + c4];
            qT[c4+0][row] = v4.x; qT[c4+1][row] = v4.y;
            qT[c4+2][row] = v4.z; qT[c4+3][row] = v4.w;
        }
        #pragma unroll
        for (int it = 0; it < 8; ++it) {
            const int ff = tid + (it << 8);
            const int row = ff >> 4, c4 = (ff & 15) << 2;
            float4 v4 = *(const float4*)&k[(base + k0 + row) * HD + c4];
            kT[c4+0][row] = v4.x; kT[c4+1][row] = v4.y;
            kT[c4+2][row] = v4.z; kT[c4+3][row] = v4.w;
        }
        if (tid < 32) {
            m_s[tid]  = m_arr[(b * NH + h) * TSEQ + q0 + tid];
            li_s[tid] = linv_arr[(b * NH + h) * TSEQ + q0 + tid];
        }
        __syncthreads();

        float acc[4][4];
        #pragma unroll
        for (int r = 0; r < 4; ++r)
            #pragma unroll
            for (int c = 0; c < 4; ++c) acc[r][c] = 0.f;

        for (int d = 0; d < 64; ++d) {
            float4 kq = *(const float4*)&kT[d][tx << 2];
            float4 qq = *(const float4*)&qT[d][ty << 2];
            float qa[4] = {qq.x, qq.y, qq.z, qq.w};
            float ka[4] = {kq.x, kq.y, kq.z, kq.w};
            #pragma unroll
            for (int r = 0; r < 4; ++r)
                #pragma unroll
                for (int c = 0; c < 4; ++c)
                    acc[r][c] = fmaf(qa[r], ka[c], acc[r][c]);
        }
        #pragma unroll
        for (int r = 0; r < 4; ++r) {
            const float mh = m_s[(ty << 2) + r];
            const float li = li_s[(ty << 2) + r];
            #pragma unroll
            for (int c = 0; c < 4; ++c) {
                const float s = acc[r][c] + padv[(tx << 2) + c];
                sum[r][c] = fmaf(EXP2((s - mh) * L2E), li, sum[r][c]);
            }
        }
    }

    const float invH = 1.0f / (float)NH;
    #pragma unroll
    for (int r = 0; r < 4; ++r) {
        const int row = q0 + (ty << 2) + r;
        float4 outv;
        outv.x = sum[r][0] * invH; outv.y = sum[r][1] * invH;
        outv.z = sum[r][2] * invH; outv.w = sum[r][3] * invH;
        *(float4*)&a_avg[((size_t)b * TSEQ + row) * TSEQ + k0 + (tx << 2)] = outv;
    }
}

// ---------------------------------------------------------------------------
extern "C" void kernel_launch(void* const* d_in, const int* in_sizes, int n_in,
                              void* d_out, int out_size, void* d_ws, size_t ws_size,
                              hipStream_t stream)
{
    const float* x    = (const float*)d_in[0];
    const float* mre  = (const float*)d_in[1];
    const float* mim  = (const float*)d_in[2];
    const float* pad  = (const float*)d_in[3];
    const float* qkvw = (const float*)d_in[4];
    const float* qkvb = (const float*)d_in[5];
    const float* ow   = (const float*)d_in[6];
    const float* ob   = (const float*)d_in[7];

    float* out_o = (float*)d_out;                    // [B,T,E] = 4194304 floats
    float* out_a = out_o + (size_t)NB * TSEQ * EMB;  // [B,T,T] = 8388608 floats

    // o_tmp borrows the a_avg output region; consumed by the o-proj GEMM
    // before attn_avg overwrites it (stream-ordered).
    float* otmp = out_a;

    // workspace layout (floats): q | k | v | m | linv  (~48.5 MB)
    float* w = (float*)d_ws;
    const size_t SZ = (size_t)NB * NH * TSEQ * HD;   // 4194304
    float* qb    = w;
    float* kb    = w + SZ;
    float* vb    = w + 2 * SZ;
    float* marr  = w + 3 * SZ;
    float* linv  = w + 3 * SZ + (size_t)NB * NH * TSEQ;

    // 1) fused QKV projection, scatter to [B,H,T,hd], q pre-scaled
    gemm_nt_kernel<<<dim3(32, 24), 256, 0, stream>>>(
        x, qkvw, qkvb, qb, kb, vb, NB * TSEQ, 3 * EMB, EMB, 1);

    // 2) rotary on k
    rotary_k_kernel<<<8192, 256, 0, stream>>>(kb, mre, mim);

    // 3) flash attention -> o_tmp [B,T,E], stats (m, 1/l)
    flash_attn_kernel<<<2048, 256, 0, stream>>>(qb, kb, vb, pad, otmp, marr, linv);

    // 4) output projection (consumes o_tmp from the a_avg region)
    gemm_nt_kernel<<<dim3(32, 8), 256, 0, stream>>>(
        otmp, ow, ob, out_o, nullptr, nullptr, NB * TSEQ, EMB, EMB, 0);

    // 5) head-averaged probs -> a_avg (overwrites the scratch region)
    attn_avg_kernel<<<dim3(TSEQ / 128, TSEQ / 32, NB), 256, 0, stream>>>(
        qb, kb, pad, marr, linv, out_a);
}

// Round 7
// 1072.719 us; speedup vs baseline: 1.8796x; 1.8796x over previous
//
#include <hip/hip_runtime.h>
#include <math.h>

#define TSEQ 2048
#define EMB  1024
#define NH   16
#define HD   64
#define NB   2
#define L2E  1.4426950408889634f

#if defined(__has_builtin)
#if __has_builtin(__builtin_amdgcn_exp2f)
#define EXP2(x) __builtin_amdgcn_exp2f(x)
#else
#define EXP2(x) exp2f(x)
#endif
#else
#define EXP2(x) exp2f(x)
#endif

typedef unsigned short u16;
typedef unsigned int   u32;
typedef __attribute__((ext_vector_type(8))) short short8v;  // 8 bf16 (4 VGPRs)
typedef __attribute__((ext_vector_type(4))) float f32x4;

#define MFMA16(a,b,c) __builtin_amdgcn_mfma_f32_16x16x32_bf16(a,b,c,0,0,0)

// ---- bf16 split helpers: x ~= hi + lo, each bf16 (RNE) --------------------
__device__ inline u32 f2bf(float x) {
    u32 u = __float_as_uint(x);
    return (u + 0x7fffu + ((u >> 16) & 1u)) >> 16;
}
__device__ inline float bf2f(u32 b) { return __uint_as_float(b << 16); }
__device__ inline void split4(float x0, float x1, float x2, float x3,
                              u32& hw0, u32& hw1, u32& lw0, u32& lw1) {
    u32 h0 = f2bf(x0), h1 = f2bf(x1), h2 = f2bf(x2), h3 = f2bf(x3);
    u32 l0 = f2bf(x0 - bf2f(h0)), l1 = f2bf(x1 - bf2f(h1));
    u32 l2 = f2bf(x2 - bf2f(h2)), l3 = f2bf(x3 - bf2f(h3));
    hw0 = h0 | (h1 << 16); hw1 = h2 | (h3 << 16);
    lw0 = l0 | (l1 << 16); lw1 = l2 | (l3 << 16);
}

// ---------------------------------------------------------------------------
// QKV GEMM (NT, fp32 core 128x128 tile): epilogue splits to bf16 hi/lo arrays.
// q: scaled 0.125, layout [B,H,T,hd]. k: [B,H,T,hd] (rotary later, in place).
// v: TRANSPOSED [B,H,hd,T] for contiguous PV B-frags.
// ---------------------------------------------------------------------------
__global__ __launch_bounds__(256) void gemm_qkv_kernel(
    const float* __restrict__ A, const float* __restrict__ B,
    const float* __restrict__ bias,
    u16* __restrict__ qhi, u16* __restrict__ qlo,
    u16* __restrict__ khi, u16* __restrict__ klo,
    u16* __restrict__ vthi, u16* __restrict__ vtlo,
    int M, int N, int K)
{
    __shared__ float As[16][132];
    __shared__ float Bs[16][132];

    const int tid = threadIdx.x;
    const int i0 = blockIdx.x * 128;
    const int j0 = blockIdx.y * 128;
    const int ty = tid >> 4, tx = tid & 15;
    const int lr = tid >> 2, lc = (tid & 3) << 2;

    const float* Ap0 = A + (size_t)(i0 + lr) * K + lc;
    const float* Ap1 = A + (size_t)(i0 + 64 + lr) * K + lc;
    const float* Bp0 = B + (size_t)(j0 + lr) * K + lc;
    const float* Bp1 = B + (size_t)(j0 + 64 + lr) * K + lc;

    float acc[2][2][4][4] = {};

    for (int k0 = 0; k0 < K; k0 += 16) {
        float4 a0 = *(const float4*)(Ap0 + k0);
        float4 a1 = *(const float4*)(Ap1 + k0);
        float4 b0 = *(const float4*)(Bp0 + k0);
        float4 b1 = *(const float4*)(Bp1 + k0);
        As[lc+0][lr] = a0.x; As[lc+1][lr] = a0.y; As[lc+2][lr] = a0.z; As[lc+3][lr] = a0.w;
        As[lc+0][64+lr] = a1.x; As[lc+1][64+lr] = a1.y; As[lc+2][64+lr] = a1.z; As[lc+3][64+lr] = a1.w;
        Bs[lc+0][lr] = b0.x; Bs[lc+1][lr] = b0.y; Bs[lc+2][lr] = b0.z; Bs[lc+3][lr] = b0.w;
        Bs[lc+0][64+lr] = b1.x; Bs[lc+1][64+lr] = b1.y; Bs[lc+2][64+lr] = b1.z; Bs[lc+3][64+lr] = b1.w;
        __syncthreads();
        #pragma unroll
        for (int kk = 0; kk < 16; ++kk) {
            float4 av0 = *(const float4*)&As[kk][ty << 2];
            float4 av1 = *(const float4*)&As[kk][64 + (ty << 2)];
            float4 bv0 = *(const float4*)&Bs[kk][tx << 2];
            float4 bv1 = *(const float4*)&Bs[kk][64 + (tx << 2)];
            float ar[2][4] = {{av0.x, av0.y, av0.z, av0.w}, {av1.x, av1.y, av1.z, av1.w}};
            float br[2][4] = {{bv0.x, bv0.y, bv0.z, bv0.w}, {bv1.x, bv1.y, bv1.z, bv1.w}};
            #pragma unroll
            for (int ri = 0; ri < 2; ++ri)
                #pragma unroll
                for (int ci = 0; ci < 2; ++ci)
                    #pragma unroll
                    for (int r = 0; r < 4; ++r)
                        #pragma unroll
                        for (int c = 0; c < 4; ++c)
                            acc[ri][ci][r][c] = fmaf(ar[ri][r], br[ci][c], acc[ri][ci][r][c]);
        }
        __syncthreads();
    }

    float4 bias4[2];
    bias4[0] = *(const float4*)&bias[j0 + (tx << 2)];
    bias4[1] = *(const float4*)&bias[j0 + 64 + (tx << 2)];

    const int which = j0 >> 10;   // whole 128-block lies in one region

    #pragma unroll
    for (int ri = 0; ri < 2; ++ri) {
        #pragma unroll
        for (int r = 0; r < 4; ++r) {
            const int i = i0 + ri * 64 + (ty << 2) + r;
            const int b = i >> 11, t = i & (TSEQ - 1);
            #pragma unroll
            for (int ci = 0; ci < 2; ++ci) {
                float v0 = acc[ri][ci][r][0] + ((ci==0)?bias4[0].x:bias4[1].x);
                float v1 = acc[ri][ci][r][1] + ((ci==0)?bias4[0].y:bias4[1].y);
                float v2 = acc[ri][ci][r][2] + ((ci==0)?bias4[0].z:bias4[1].z);
                float v3 = acc[ri][ci][r][3] + ((ci==0)?bias4[0].w:bias4[1].w);
                const int j = j0 + ci * 64 + (tx << 2);
                const int e = j & (EMB - 1);
                const int h = e >> 6, d = e & (HD - 1);
                if (which == 0) { v0 *= 0.125f; v1 *= 0.125f; v2 *= 0.125f; v3 *= 0.125f; }
                u32 hw0, hw1, lw0, lw1;
                split4(v0, v1, v2, v3, hw0, hw1, lw0, lw1);
                if (which == 2) {
                    // transposed scatter: vt[((b*NH+h)*HD + d+cc)*TSEQ + t]
                    const size_t tb = ((size_t)(b * NH + h) * HD + d) * TSEQ + t;
                    vthi[tb]          = (u16)(hw0 & 0xffff);
                    vthi[tb + TSEQ]   = (u16)(hw0 >> 16);
                    vthi[tb + 2*TSEQ] = (u16)(hw1 & 0xffff);
                    vthi[tb + 3*TSEQ] = (u16)(hw1 >> 16);
                    vtlo[tb]          = (u16)(lw0 & 0xffff);
                    vtlo[tb + TSEQ]   = (u16)(lw0 >> 16);
                    vtlo[tb + 2*TSEQ] = (u16)(lw1 & 0xffff);
                    vtlo[tb + 3*TSEQ] = (u16)(lw1 >> 16);
                } else {
                    const size_t ix = ((size_t)(b * NH + h) * TSEQ + t) * HD + d;
                    u16* dh = (which == 0) ? qhi : khi;
                    u16* dl = (which == 0) ? qlo : klo;
                    *(u32*)(dh + ix)     = hw0;
                    *(u32*)(dh + ix + 2) = hw1;
                    *(u32*)(dl + ix)     = lw0;
                    *(u32*)(dl + ix + 2) = lw1;
                }
            }
        }
    }
}

// ---------------------------------------------------------------------------
// Output projection GEMM (fp32, unchanged core).
// ---------------------------------------------------------------------------
__global__ __launch_bounds__(256) void gemm_out_kernel(
    const float* __restrict__ A, const float* __restrict__ B,
    const float* __restrict__ bias, float* __restrict__ C,
    int M, int N, int K)
{
    __shared__ float As[16][132];
    __shared__ float Bs[16][132];

    const int tid = threadIdx.x;
    const int i0 = blockIdx.x * 128;
    const int j0 = blockIdx.y * 128;
    const int ty = tid >> 4, tx = tid & 15;
    const int lr = tid >> 2, lc = (tid & 3) << 2;

    const float* Ap0 = A + (size_t)(i0 + lr) * K + lc;
    const float* Ap1 = A + (size_t)(i0 + 64 + lr) * K + lc;
    const float* Bp0 = B + (size_t)(j0 + lr) * K + lc;
    const float* Bp1 = B + (size_t)(j0 + 64 + lr) * K + lc;

    float acc[2][2][4][4] = {};

    for (int k0 = 0; k0 < K; k0 += 16) {
        float4 a0 = *(const float4*)(Ap0 + k0);
        float4 a1 = *(const float4*)(Ap1 + k0);
        float4 b0 = *(const float4*)(Bp0 + k0);
        float4 b1 = *(const float4*)(Bp1 + k0);
        As[lc+0][lr] = a0.x; As[lc+1][lr] = a0.y; As[lc+2][lr] = a0.z; As[lc+3][lr] = a0.w;
        As[lc+0][64+lr] = a1.x; As[lc+1][64+lr] = a1.y; As[lc+2][64+lr] = a1.z; As[lc+3][64+lr] = a1.w;
        Bs[lc+0][lr] = b0.x; Bs[lc+1][lr] = b0.y; Bs[lc+2][lr] = b0.z; Bs[lc+3][lr] = b0.w;
        Bs[lc+0][64+lr] = b1.x; Bs[lc+1][64+lr] = b1.y; Bs[lc+2][64+lr] = b1.z; Bs[lc+3][64+lr] = b1.w;
        __syncthreads();
        #pragma unroll
        for (int kk = 0; kk < 16; ++kk) {
            float4 av0 = *(const float4*)&As[kk][ty << 2];
            float4 av1 = *(const float4*)&As[kk][64 + (ty << 2)];
            float4 bv0 = *(const float4*)&Bs[kk][tx << 2];
            float4 bv1 = *(const float4*)&Bs[kk][64 + (tx << 2)];
            float ar[2][4] = {{av0.x, av0.y, av0.z, av0.w}, {av1.x, av1.y, av1.z, av1.w}};
            float br[2][4] = {{bv0.x, bv0.y, bv0.z, bv0.w}, {bv1.x, bv1.y, bv1.z, bv1.w}};
            #pragma unroll
            for (int ri = 0; ri < 2; ++ri)
                #pragma unroll
                for (int ci = 0; ci < 2; ++ci)
                    #pragma unroll
                    for (int r = 0; r < 4; ++r)
                        #pragma unroll
                        for (int c = 0; c < 4; ++c)
                            acc[ri][ci][r][c] = fmaf(ar[ri][r], br[ci][c], acc[ri][ci][r][c]);
        }
        __syncthreads();
    }

    float4 bias4[2];
    bias4[0] = *(const float4*)&bias[j0 + (tx << 2)];
    bias4[1] = *(const float4*)&bias[j0 + 64 + (tx << 2)];

    #pragma unroll
    for (int ri = 0; ri < 2; ++ri) {
        #pragma unroll
        for (int r = 0; r < 4; ++r) {
            const int i = i0 + ri * 64 + (ty << 2) + r;
            #pragma unroll
            for (int ci = 0; ci < 2; ++ci) {
                float4 val;
                val.x = acc[ri][ci][r][0] + ((ci==0)?bias4[0].x:bias4[1].x);
                val.y = acc[ri][ci][r][1] + ((ci==0)?bias4[0].y:bias4[1].y);
                val.z = acc[ri][ci][r][2] + ((ci==0)?bias4[0].z:bias4[1].z);
                val.w = acc[ri][ci][r][3] + ((ci==0)?bias4[0].w:bias4[1].w);
                *(float4*)&C[(size_t)i * N + j0 + ci * 64 + (tx << 2)] = val;
            }
        }
    }
}

// ---------------------------------------------------------------------------
// Rotary on split-bf16 k, in place.
// ---------------------------------------------------------------------------
__global__ __launch_bounds__(256) void rotary_k_kernel(
    u16* __restrict__ khi, u16* __restrict__ klo,
    const float* __restrict__ mre, const float* __restrict__ mim)
{
    const int idx = blockIdx.x * 256 + threadIdx.x;   // pair index
    const int d2 = idx & 31;
    const int t  = (idx >> 5) & (TSEQ - 1);
    const int b  = idx >> 20;
    u32 h2 = *(u32*)(khi + ((size_t)idx << 1));
    u32 l2 = *(u32*)(klo + ((size_t)idx << 1));
    float kr = bf2f(h2 & 0xffff) + bf2f(l2 & 0xffff);
    float ki = bf2f(h2 >> 16) + bf2f(l2 >> 16);
    const int mix = (b * TSEQ + t) * 32 + d2;
    const float mr = mre[mix], mi = mim[mix];
    float rr = kr * mr - ki * mi;
    float ri = kr * mi + ki * mr;
    u32 hr = f2bf(rr), hx = f2bf(ri);
    u32 lr = f2bf(rr - bf2f(hr)), lx = f2bf(ri - bf2f(hx));
    *(u32*)(khi + ((size_t)idx << 1)) = hr | (hx << 16);
    *(u32*)(klo + ((size_t)idx << 1)) = lr | (lx << 16);
}

// ---------------------------------------------------------------------------
// MFMA flash attention, split-bf16 (3-term), barrier-free.
// 128 thr = 2 waves; each wave owns 32 q-rows of one (b,h); kv tiles of 32.
// Frags read directly from global (L1/L2-hot); P roundtrips per-wave LDS.
// A-frag: row=lane&15, k=(lane>>4)*8+j. B-frag: col=lane&15, same k map.
// C/D: col=lane&15, row=(lane>>4)*4+reg (HW-verified).
// ---------------------------------------------------------------------------
__global__ __launch_bounds__(128) void flash_attn_kernel(
    const u16* __restrict__ qhi_, const u16* __restrict__ qlo_,
    const u16* __restrict__ khi_, const u16* __restrict__ klo_,
    const u16* __restrict__ vthi_, const u16* __restrict__ vtlo_,
    const float* __restrict__ pad,
    float* __restrict__ o_tmp, float* __restrict__ m_out,
    float* __restrict__ linv_out)
{
    __shared__ __align__(16) u16 Phi[2][32*40];
    __shared__ __align__(16) u16 Plo[2][32*40];

    const int tid  = threadIdx.x;
    const int lane = tid & 63;
    const int w    = tid >> 6;
    const int bh   = blockIdx.x >> 5;
    const int sub  = blockIdx.x & 31;
    const int b    = bh >> 4, h = bh & (NH - 1);
    const int qbase = sub * 64 + w * 32;
    const int lg = lane >> 4, lc = lane & 15;

    // preload q A-frags [qset][kstep]
    short8v qh[2][2], ql[2][2];
    #pragma unroll
    for (int qs = 0; qs < 2; ++qs) {
        const size_t qoff = ((size_t)bh * TSEQ + qbase + qs*16 + lc) * HD + lg*8;
        #pragma unroll
        for (int s = 0; s < 2; ++s) {
            qh[qs][s] = *(const short8v*)(qhi_ + qoff + s*32);
            ql[qs][s] = *(const short8v*)(qlo_ + qoff + s*32);
        }
    }

    f32x4 O[2][4];
    float mst[2][4], lst[2][4];
    #pragma unroll
    for (int qs = 0; qs < 2; ++qs) {
        #pragma unroll
        for (int db = 0; db < 4; ++db) O[qs][db] = (f32x4){0.f,0.f,0.f,0.f};
        #pragma unroll
        for (int r = 0; r < 4; ++r) { mst[qs][r] = -1e30f; lst[qs][r] = 0.f; }
    }

    u16* PHw = &Phi[w][0];
    u16* PLw = &Plo[w][0];
    const size_t kbase  = (size_t)bh * TSEQ * HD;
    const size_t vtbase = (size_t)bh * HD * TSEQ;

    for (int k0 = 0; k0 < TSEQ; k0 += 32) {
        // ---- QK^T: S[qs][keyblock], 24 MFMA ----
        f32x4 S[2][2];
        #pragma unroll
        for (int qs = 0; qs < 2; ++qs)
            #pragma unroll
            for (int kb2 = 0; kb2 < 2; ++kb2) S[qs][kb2] = (f32x4){0.f,0.f,0.f,0.f};
        #pragma unroll
        for (int kb2 = 0; kb2 < 2; ++kb2) {
            #pragma unroll
            for (int s = 0; s < 2; ++s) {
                const size_t ko = kbase + (size_t)(k0 + kb2*16 + lc) * HD + s*32 + lg*8;
                short8v kh = *(const short8v*)(khi_ + ko);
                short8v kl = *(const short8v*)(klo_ + ko);
                #pragma unroll
                for (int qs = 0; qs < 2; ++qs) {
                    S[qs][kb2] = MFMA16(qh[qs][s], kh, S[qs][kb2]);
                    S[qs][kb2] = MFMA16(qh[qs][s], kl, S[qs][kb2]);
                    S[qs][kb2] = MFMA16(ql[qs][s], kh, S[qs][kb2]);
                }
            }
        }

        const float pv0 = pad[b * TSEQ + k0 + lc];
        const float pv1 = pad[b * TSEQ + k0 + 16 + lc];

        // ---- online softmax (rows = lg*4+r within qset), P write, rescale ----
        #pragma unroll
        for (int qs = 0; qs < 2; ++qs) {
            #pragma unroll
            for (int r = 0; r < 4; ++r) {
                float s0 = S[qs][0][r] + pv0;
                float s1 = S[qs][1][r] + pv1;
                float t = fmaxf(s0, s1);
                t = fmaxf(t, __shfl_xor(t, 1));
                t = fmaxf(t, __shfl_xor(t, 2));
                t = fmaxf(t, __shfl_xor(t, 4));
                t = fmaxf(t, __shfl_xor(t, 8));
                const float mn = fmaxf(mst[qs][r], t);
                const float cc = EXP2((mst[qs][r] - mn) * L2E);
                const float p0 = EXP2((s0 - mn) * L2E);
                const float p1 = EXP2((s1 - mn) * L2E);
                float ps = p0 + p1;
                ps += __shfl_xor(ps, 1);
                ps += __shfl_xor(ps, 2);
                ps += __shfl_xor(ps, 4);
                ps += __shfl_xor(ps, 8);
                lst[qs][r] = lst[qs][r] * cc + ps;
                mst[qs][r] = mn;
                const int row = qs*16 + lg*4 + r;
                const u32 h0 = f2bf(p0), h1 = f2bf(p1);
                PHw[row*40 + lc]      = (u16)h0;
                PHw[row*40 + 16 + lc] = (u16)h1;
                PLw[row*40 + lc]      = (u16)f2bf(p0 - bf2f(h0));
                PLw[row*40 + 16 + lc] = (u16)f2bf(p1 - bf2f(h1));
                #pragma unroll
                for (int db = 0; db < 4; ++db) O[qs][db][r] *= cc;
            }
        }

        // ---- P A-frags (within-wave LDS roundtrip re-layout) ----
        short8v pfh[2], pfl[2];
        #pragma unroll
        for (int qs = 0; qs < 2; ++qs) {
            pfh[qs] = *(const short8v*)(PHw + (qs*16 + lc)*40 + lg*8);
            pfl[qs] = *(const short8v*)(PLw + (qs*16 + lc)*40 + lg*8);
        }

        // ---- PV: 24 MFMA ----
        #pragma unroll
        for (int db = 0; db < 4; ++db) {
            const size_t vo = vtbase + (size_t)(db*16 + lc) * TSEQ + k0 + lg*8;
            short8v vh = *(const short8v*)(vthi_ + vo);
            short8v vl = *(const short8v*)(vtlo_ + vo);
            #pragma unroll
            for (int qs = 0; qs < 2; ++qs) {
                O[qs][db] = MFMA16(pfh[qs], vh, O[qs][db]);
                O[qs][db] = MFMA16(pfh[qs], vl, O[qs][db]);
                O[qs][db] = MFMA16(pfl[qs], vh, O[qs][db]);
            }
        }
    }

    // ---- epilogue ----
    #pragma unroll
    for (int qs = 0; qs < 2; ++qs) {
        #pragma unroll
        for (int r = 0; r < 4; ++r) {
            const float inv = 1.f / lst[qs][r];
            const int trow = qbase + qs*16 + lg*4 + r;
            float* op = o_tmp + ((size_t)(b * TSEQ + trow)) * EMB + h * HD;
            #pragma unroll
            for (int db = 0; db < 4; ++db)
                op[db*16 + lc] = O[qs][db][r] * inv;
            if (lc == 0) {
                m_out[bh * TSEQ + trow] = mst[qs][r];
                linv_out[bh * TSEQ + trow] = inv;
            }
        }
    }
}

// ---------------------------------------------------------------------------
// a_avg via MFMA score recompute + saved stats. Barrier-free, no LDS.
// Block: (b, q-tile 32, k-tile 128); wave w covers keys w*32..w*32+31.
// ---------------------------------------------------------------------------
__global__ __launch_bounds__(256) void attn_avg_kernel(
    const u16* __restrict__ qhi_, const u16* __restrict__ qlo_,
    const u16* __restrict__ khi_, const u16* __restrict__ klo_,
    const float* __restrict__ pad, const float* __restrict__ m_arr,
    const float* __restrict__ linv_arr, float* __restrict__ a_avg)
{
    const int tid  = threadIdx.x;
    const int lane = tid & 63;
    const int w    = tid >> 6;
    const int b  = blockIdx.z;
    const int q0 = blockIdx.y << 5;
    const int k0 = blockIdx.x << 7;
    const int lg = lane >> 4, lc = lane & 15;
    const int kw = k0 + w * 32;

    const float pv0 = pad[b * TSEQ + kw + lc];
    const float pv1 = pad[b * TSEQ + kw + 16 + lc];

    f32x4 acc[2][2];
    #pragma unroll
    for (int qs = 0; qs < 2; ++qs)
        #pragma unroll
        for (int kb2 = 0; kb2 < 2; ++kb2) acc[qs][kb2] = (f32x4){0.f,0.f,0.f,0.f};

    for (int h = 0; h < NH; ++h) {
        const size_t hb = (size_t)(b * NH + h) * TSEQ;
        short8v qh[2][2], ql[2][2];
        #pragma unroll
        for (int qs = 0; qs < 2; ++qs) {
            const size_t qoff = (hb + q0 + qs*16 + lc) * HD + lg*8;
            #pragma unroll
            for (int s = 0; s < 2; ++s) {
                qh[qs][s] = *(const short8v*)(qhi_ + qoff + s*32);
                ql[qs][s] = *(const short8v*)(qlo_ + qoff + s*32);
            }
        }
        f32x4 S[2][2];
        #pragma unroll
        for (int qs = 0; qs < 2; ++qs)
            #pragma unroll
            for (int kb2 = 0; kb2 < 2; ++kb2) S[qs][kb2] = (f32x4){0.f,0.f,0.f,0.f};
        #pragma unroll
        for (int kb2 = 0; kb2 < 2; ++kb2) {
            #pragma unroll
            for (int s = 0; s < 2; ++s) {
                const size_t ko = (hb + kw + kb2*16 + lc) * HD + s*32 + lg*8;
                short8v kh = *(const short8v*)(khi_ + ko);
                short8v kl = *(const short8v*)(klo_ + ko);
                #pragma unroll
                for (int qs = 0; qs < 2; ++qs) {
                    S[qs][kb2] = MFMA16(qh[qs][s], kh, S[qs][kb2]);
                    S[qs][kb2] = MFMA16(qh[qs][s], kl, S[qs][kb2]);
                    S[qs][kb2] = MFMA16(ql[qs][s], kh, S[qs][kb2]);
                }
            }
        }
        #pragma unroll
        for (int qs = 0; qs < 2; ++qs) {
            #pragma unroll
            for (int r = 0; r < 4; ++r) {
                const size_t rix = hb + q0 + qs*16 + lg*4 + r;
                const float mh = m_arr[rix];
                const float li = linv_arr[rix];
                acc[qs][0][r] += EXP2((S[qs][0][r] + pv0 - mh) * L2E) * li;
                acc[qs][1][r] += EXP2((S[qs][1][r] + pv1 - mh) * L2E) * li;
            }
        }
    }

    const float invH = 1.0f / (float)NH;
    #pragma unroll
    for (int qs = 0; qs < 2; ++qs) {
        #pragma unroll
        for (int r = 0; r < 4; ++r) {
            const int row = q0 + qs*16 + lg*4 + r;
            #pragma unroll
            for (int kb2 = 0; kb2 < 2; ++kb2)
                a_avg[((size_t)b * TSEQ + row) * TSEQ + kw + kb2*16 + lc] =
                    acc[qs][kb2][r] * invH;
        }
    }
}

// ---------------------------------------------------------------------------
extern "C" void kernel_launch(void* const* d_in, const int* in_sizes, int n_in,
                              void* d_out, int out_size, void* d_ws, size_t ws_size,
                              hipStream_t stream)
{
    const float* x    = (const float*)d_in[0];
    const float* mre  = (const float*)d_in[1];
    const float* mim  = (const float*)d_in[2];
    const float* pad  = (const float*)d_in[3];
    const float* qkvw = (const float*)d_in[4];
    const float* qkvb = (const float*)d_in[5];
    const float* ow   = (const float*)d_in[6];
    const float* ob   = (const float*)d_in[7];

    float* out_o = (float*)d_out;                    // [B,T,E]
    float* out_a = out_o + (size_t)NB * TSEQ * EMB;  // [B,T,T]
    float* otmp  = out_a;   // borrowed; consumed by o-proj before attn_avg

    // ws: 6 split-bf16 arrays (8 MB each) + stats = 48.5 MB
    const size_t SZ = (size_t)NB * NH * TSEQ * HD;   // 4194304
    u16* qhi  = (u16*)d_ws;
    u16* qlo  = qhi  + SZ;
    u16* khi  = qlo  + SZ;
    u16* klo  = khi  + SZ;
    u16* vthi = klo  + SZ;
    u16* vtlo = vthi + SZ;
    float* marr = (float*)(vtlo + SZ);
    float* linv = marr + (size_t)NB * NH * TSEQ;

    // 1) QKV projection -> split-bf16 q/k (BHTd) + v transposed (BHdT)
    gemm_qkv_kernel<<<dim3(32, 24), 256, 0, stream>>>(
        x, qkvw, qkvb, qhi, qlo, khi, klo, vthi, vtlo, NB * TSEQ, 3 * EMB, EMB);

    // 2) rotary on k (in place, split-bf16)
    rotary_k_kernel<<<8192, 256, 0, stream>>>(khi, klo, mre, mim);

    // 3) MFMA flash attention -> o_tmp [B,T,E] + stats
    flash_attn_kernel<<<1024, 128, 0, stream>>>(
        qhi, qlo, khi, klo, vthi, vtlo, pad, otmp, marr, linv);

    // 4) output projection (consumes o_tmp)
    gemm_out_kernel<<<dim3(32, 8), 256, 0, stream>>>(
        otmp, ow, ob, out_o, NB * TSEQ, EMB, EMB);

    // 5) head-averaged probs -> a_avg (overwrites scratch region)
    attn_avg_kernel<<<dim3(16, 64, 2), 256, 0, stream>>>(
        qhi, qlo, khi, klo, pad, marr, linv, out_a);
}

// Round 8
// 796.116 us; speedup vs baseline: 2.5326x; 1.3474x over previous
//
#include <hip/hip_runtime.h>
#include <math.h>

#define TSEQ 2048
#define EMB  1024
#define NH   16
#define HD   64
#define NB   2
#define L2E  1.4426950408889634f

#if defined(__has_builtin)
#if __has_builtin(__builtin_amdgcn_exp2f)
#define EXP2(x) __builtin_amdgcn_exp2f(x)
#else
#define EXP2(x) exp2f(x)
#endif
#else
#define EXP2(x) exp2f(x)
#endif

typedef unsigned short u16;
typedef unsigned int   u32;
typedef __attribute__((ext_vector_type(8))) short short8v;  // 8 bf16
typedef __attribute__((ext_vector_type(4))) float f32x4;

#define MFMA16(a,b,c) __builtin_amdgcn_mfma_f32_16x16x32_bf16(a,b,c,0,0,0)

// ---- bf16 split helpers ---------------------------------------------------
__device__ inline u32 f2bf(float x) {
    u32 u = __float_as_uint(x);
    return (u + 0x7fffu + ((u >> 16) & 1u)) >> 16;
}
__device__ inline float bf2f(u32 b) { return __uint_as_float(b << 16); }
__device__ inline void split4(float x0, float x1, float x2, float x3,
                              u32& hw0, u32& hw1, u32& lw0, u32& lw1) {
    u32 h0 = f2bf(x0), h1 = f2bf(x1), h2 = f2bf(x2), h3 = f2bf(x3);
    u32 l0 = f2bf(x0 - bf2f(h0)), l1 = f2bf(x1 - bf2f(h1));
    u32 l2 = f2bf(x2 - bf2f(h2)), l3 = f2bf(x3 - bf2f(h3));
    hw0 = h0 | (h1 << 16); hw1 = h2 | (h3 << 16);
    lw0 = l0 | (l1 << 16); lw1 = l2 | (l3 << 16);
}

// ---------------------------------------------------------------------------
// fp32 -> split bf16 hi/lo. n4 = n/4 elements, exact grid.
// ---------------------------------------------------------------------------
__global__ __launch_bounds__(256) void conv_split_kernel(
    const float* __restrict__ in, u16* __restrict__ hi, u16* __restrict__ lo)
{
    const size_t i = (size_t)blockIdx.x * 256 + threadIdx.x;
    float4 v = ((const float4*)in)[i];
    u32 hw0, hw1, lw0, lw1;
    split4(v.x, v.y, v.z, v.w, hw0, hw1, lw0, lw1);
    *(uint2*)(hi + i * 4) = make_uint2(hw0, hw1);
    *(uint2*)(lo + i * 4) = make_uint2(lw0, lw1);
}

// ---------------------------------------------------------------------------
// Split-bf16 MFMA GEMM NT core: C = A * B^T (+bias in epilogue).
// Block 256 thr = 4 waves (2x2), tile 128x128, per-wave 64x64 (4x4 frags),
// BK=32. LDS stride 40 u16 (16B-aligned rows, 2-way max on frag reads).
// 48 MFMA : 16 ds_read_b128 per wave-kstep.
// ---------------------------------------------------------------------------
#define MM_CORE(Ah_, Al_, Bh_, Bl_, Kdim)                                      \
    __shared__ __align__(16) u16 sAh[128][40], sAl[128][40];                   \
    __shared__ __align__(16) u16 sBh[128][40], sBl[128][40];                   \
    const int tid = threadIdx.x;                                               \
    const int lane = tid & 63, w = tid >> 6;                                   \
    const int lc = lane & 15, lg = lane >> 4;                                  \
    const int wr = w >> 1, wc = w & 1;                                         \
    const int i0 = blockIdx.x * 128, j0 = blockIdx.y * 128;                    \
    const int srow = tid >> 1, shalf = (tid & 1) << 4;                         \
    const u16* pAh = Ah_ + (size_t)(i0 + srow) * Kdim + shalf;                 \
    const u16* pAl = Al_ + (size_t)(i0 + srow) * Kdim + shalf;                 \
    const u16* pBh = Bh_ + (size_t)(j0 + srow) * Kdim + shalf;                 \
    const u16* pBl = Bl_ + (size_t)(j0 + srow) * Kdim + shalf;                 \
    f32x4 acc[4][4];                                                           \
    _Pragma("unroll")                                                          \
    for (int rs = 0; rs < 4; ++rs)                                             \
        _Pragma("unroll")                                                      \
        for (int cs = 0; cs < 4; ++cs) acc[rs][cs] = (f32x4){0.f,0.f,0.f,0.f};\
    for (int k0 = 0; k0 < Kdim; k0 += 32) {                                    \
        short8v va0 = *(const short8v*)(pAh + k0);                             \
        short8v va1 = *(const short8v*)(pAh + k0 + 8);                         \
        short8v vb0 = *(const short8v*)(pAl + k0);                             \
        short8v vb1 = *(const short8v*)(pAl + k0 + 8);                         \
        short8v vc0 = *(const short8v*)(pBh + k0);                             \
        short8v vc1 = *(const short8v*)(pBh + k0 + 8);                         \
        short8v vd0 = *(const short8v*)(pBl + k0);                             \
        short8v vd1 = *(const short8v*)(pBl + k0 + 8);                         \
        *(short8v*)&sAh[srow][shalf]     = va0;                                \
        *(short8v*)&sAh[srow][shalf + 8] = va1;                                \
        *(short8v*)&sAl[srow][shalf]     = vb0;                                \
        *(short8v*)&sAl[srow][shalf + 8] = vb1;                                \
        *(short8v*)&sBh[srow][shalf]     = vc0;                                \
        *(short8v*)&sBh[srow][shalf + 8] = vc1;                                \
        *(short8v*)&sBl[srow][shalf]     = vd0;                                \
        *(short8v*)&sBl[srow][shalf + 8] = vd1;                                \
        __syncthreads();                                                       \
        short8v fah[4], fal[4], fbh[4], fbl[4];                                \
        _Pragma("unroll")                                                      \
        for (int rs = 0; rs < 4; ++rs) {                                       \
            fah[rs] = *(const short8v*)&sAh[wr*64 + rs*16 + lc][lg*8];         \
            fal[rs] = *(const short8v*)&sAl[wr*64 + rs*16 + lc][lg*8];         \
        }                                                                      \
        _Pragma("unroll")                                                      \
        for (int cs = 0; cs < 4; ++cs) {                                       \
            fbh[cs] = *(const short8v*)&sBh[wc*64 + cs*16 + lc][lg*8];         \
            fbl[cs] = *(const short8v*)&sBl[wc*64 + cs*16 + lc][lg*8];         \
        }                                                                      \
        _Pragma("unroll")                                                      \
        for (int rs = 0; rs < 4; ++rs)                                         \
            _Pragma("unroll")                                                  \
            for (int cs = 0; cs < 4; ++cs) {                                   \
                acc[rs][cs] = MFMA16(fah[rs], fbh[cs], acc[rs][cs]);           \
                acc[rs][cs] = MFMA16(fah[rs], fbl[cs], acc[rs][cs]);           \
                acc[rs][cs] = MFMA16(fal[rs], fbh[cs], acc[rs][cs]);           \
            }                                                                  \
        __syncthreads();                                                       \
    }

// QKV projection: A = x-split [4096][1024], B = qkv_w-split [3072][1024].
// Epilogue scatters split-bf16 q (x0.125) / k / v-transposed.
__global__ __launch_bounds__(256) void mm_qkv_kernel(
    const u16* __restrict__ Ah, const u16* __restrict__ Al,
    const u16* __restrict__ Bh, const u16* __restrict__ Bl,
    const float* __restrict__ bias,
    u16* __restrict__ qhi, u16* __restrict__ qlo,
    u16* __restrict__ khi, u16* __restrict__ klo,
    u16* __restrict__ vthi, u16* __restrict__ vtlo)
{
    MM_CORE(Ah, Al, Bh, Bl, EMB)

    const int which = j0 >> 10;
    #pragma unroll
    for (int cs = 0; cs < 4; ++cs) {
        const int j = j0 + wc*64 + cs*16 + lc;
        const float bj = bias[j];
        const int e = j & (EMB - 1);
        const int hh = e >> 6, d = e & (HD - 1);
        #pragma unroll
        for (int rs = 0; rs < 4; ++rs) {
            #pragma unroll
            for (int r = 0; r < 4; ++r) {
                const int i = i0 + wr*64 + rs*16 + lg*4 + r;
                const int b = i >> 11, t = i & (TSEQ - 1);
                float val = acc[rs][cs][r] + bj;
                if (which == 0) val *= 0.125f;
                const u32 vh = f2bf(val);
                const u32 vl = f2bf(val - bf2f(vh));
                if (which == 2) {
                    const size_t ix = ((size_t)(b * NH + hh) * HD + d) * TSEQ + t;
                    vthi[ix] = (u16)vh; vtlo[ix] = (u16)vl;
                } else {
                    const size_t ix = ((size_t)(b * NH + hh) * TSEQ + t) * HD + d;
                    if (which == 0) { qhi[ix] = (u16)vh; qlo[ix] = (u16)vl; }
                    else            { khi[ix] = (u16)vh; klo[ix] = (u16)vl; }
                }
            }
        }
    }
}

// Output projection: A = o-split [4096][1024], B = o_w-split [1024][1024].
__global__ __launch_bounds__(256) void mm_out_kernel(
    const u16* __restrict__ Ah, const u16* __restrict__ Al,
    const u16* __restrict__ Bh, const u16* __restrict__ Bl,
    const float* __restrict__ bias, float* __restrict__ C)
{
    MM_CORE(Ah, Al, Bh, Bl, EMB)

    #pragma unroll
    for (int cs = 0; cs < 4; ++cs) {
        const int j = j0 + wc*64 + cs*16 + lc;
        const float bj = bias[j];
        #pragma unroll
        for (int rs = 0; rs < 4; ++rs) {
            #pragma unroll
            for (int r = 0; r < 4; ++r) {
                const int i = i0 + wr*64 + rs*16 + lg*4 + r;
                C[(size_t)i * EMB + j] = acc[rs][cs][r] + bj;
            }
        }
    }
}

// ---------------------------------------------------------------------------
// Rotary on split-bf16 k, in place.
// ---------------------------------------------------------------------------
__global__ __launch_bounds__(256) void rotary_k_kernel(
    u16* __restrict__ khi, u16* __restrict__ klo,
    const float* __restrict__ mre, const float* __restrict__ mim)
{
    const int idx = blockIdx.x * 256 + threadIdx.x;   // pair index
    const int d2 = idx & 31;
    const int t  = (idx >> 5) & (TSEQ - 1);
    const int b  = idx >> 20;
    u32 h2 = *(u32*)(khi + ((size_t)idx << 1));
    u32 l2 = *(u32*)(klo + ((size_t)idx << 1));
    float kr = bf2f(h2 & 0xffff) + bf2f(l2 & 0xffff);
    float ki = bf2f(h2 >> 16) + bf2f(l2 >> 16);
    const int mix = (b * TSEQ + t) * 32 + d2;
    const float mr = mre[mix], mi = mim[mix];
    float rr = kr * mr - ki * mi;
    float ri = kr * mi + ki * mr;
    u32 hr = f2bf(rr), hx = f2bf(ri);
    u32 lr = f2bf(rr - bf2f(hr)), lx = f2bf(ri - bf2f(hx));
    *(u32*)(khi + ((size_t)idx << 1)) = hr | (hx << 16);
    *(u32*)(klo + ((size_t)idx << 1)) = lr | (lx << 16);
}

// ---------------------------------------------------------------------------
// MFMA flash attention, split-bf16 (3-term), barrier-free.
// 128 thr = 2 waves; each wave owns 32 q-rows of one (b,h); kv tiles of 32.
// Writes o as SPLIT-BF16 (ohi/olo) + per-row stats.
// ---------------------------------------------------------------------------
__global__ __launch_bounds__(128) void flash_attn_kernel(
    const u16* __restrict__ qhi_, const u16* __restrict__ qlo_,
    const u16* __restrict__ khi_, const u16* __restrict__ klo_,
    const u16* __restrict__ vthi_, const u16* __restrict__ vtlo_,
    const float* __restrict__ pad,
    u16* __restrict__ ohi, u16* __restrict__ olo,
    float* __restrict__ m_out, float* __restrict__ linv_out)
{
    __shared__ __align__(16) u16 Phi[2][32*40];
    __shared__ __align__(16) u16 Plo[2][32*40];

    const int tid  = threadIdx.x;
    const int lane = tid & 63;
    const int w    = tid >> 6;
    const int bh   = blockIdx.x >> 5;
    const int sub  = blockIdx.x & 31;
    const int b    = bh >> 4, h = bh & (NH - 1);
    const int qbase = sub * 64 + w * 32;
    const int lg = lane >> 4, lc = lane & 15;

    short8v qh[2][2], ql[2][2];
    #pragma unroll
    for (int qs = 0; qs < 2; ++qs) {
        const size_t qoff = ((size_t)bh * TSEQ + qbase + qs*16 + lc) * HD + lg*8;
        #pragma unroll
        for (int s = 0; s < 2; ++s) {
            qh[qs][s] = *(const short8v*)(qhi_ + qoff + s*32);
            ql[qs][s] = *(const short8v*)(qlo_ + qoff + s*32);
        }
    }

    f32x4 O[2][4];
    float mst[2][4], lst[2][4];
    #pragma unroll
    for (int qs = 0; qs < 2; ++qs) {
        #pragma unroll
        for (int db = 0; db < 4; ++db) O[qs][db] = (f32x4){0.f,0.f,0.f,0.f};
        #pragma unroll
        for (int r = 0; r < 4; ++r) { mst[qs][r] = -1e30f; lst[qs][r] = 0.f; }
    }

    u16* PHw = &Phi[w][0];
    u16* PLw = &Plo[w][0];
    const size_t kbase  = (size_t)bh * TSEQ * HD;
    const size_t vtbase = (size_t)bh * HD * TSEQ;

    for (int k0 = 0; k0 < TSEQ; k0 += 32) {
        f32x4 S[2][2];
        #pragma unroll
        for (int qs = 0; qs < 2; ++qs)
            #pragma unroll
            for (int kb2 = 0; kb2 < 2; ++kb2) S[qs][kb2] = (f32x4){0.f,0.f,0.f,0.f};
        #pragma unroll
        for (int kb2 = 0; kb2 < 2; ++kb2) {
            #pragma unroll
            for (int s = 0; s < 2; ++s) {
                const size_t ko = kbase + (size_t)(k0 + kb2*16 + lc) * HD + s*32 + lg*8;
                short8v kh = *(const short8v*)(khi_ + ko);
                short8v kl = *(const short8v*)(klo_ + ko);
                #pragma unroll
                for (int qs = 0; qs < 2; ++qs) {
                    S[qs][kb2] = MFMA16(qh[qs][s], kh, S[qs][kb2]);
                    S[qs][kb2] = MFMA16(qh[qs][s], kl, S[qs][kb2]);
                    S[qs][kb2] = MFMA16(ql[qs][s], kh, S[qs][kb2]);
                }
            }
        }

        const float pv0 = pad[b * TSEQ + k0 + lc];
        const float pv1 = pad[b * TSEQ + k0 + 16 + lc];

        #pragma unroll
        for (int qs = 0; qs < 2; ++qs) {
            #pragma unroll
            for (int r = 0; r < 4; ++r) {
                float s0 = S[qs][0][r] + pv0;
                float s1 = S[qs][1][r] + pv1;
                float t = fmaxf(s0, s1);
                t = fmaxf(t, __shfl_xor(t, 1));
                t = fmaxf(t, __shfl_xor(t, 2));
                t = fmaxf(t, __shfl_xor(t, 4));
                t = fmaxf(t, __shfl_xor(t, 8));
                const float mn = fmaxf(mst[qs][r], t);
                const float cc = EXP2((mst[qs][r] - mn) * L2E);
                const float p0 = EXP2((s0 - mn) * L2E);
                const float p1 = EXP2((s1 - mn) * L2E);
                float ps = p0 + p1;
                ps += __shfl_xor(ps, 1);
                ps += __shfl_xor(ps, 2);
                ps += __shfl_xor(ps, 4);
                ps += __shfl_xor(ps, 8);
                lst[qs][r] = lst[qs][r] * cc + ps;
                mst[qs][r] = mn;
                const int row = qs*16 + lg*4 + r;
                const u32 h0 = f2bf(p0), h1 = f2bf(p1);
                PHw[row*40 + lc]      = (u16)h0;
                PHw[row*40 + 16 + lc] = (u16)h1;
                PLw[row*40 + lc]      = (u16)f2bf(p0 - bf2f(h0));
                PLw[row*40 + 16 + lc] = (u16)f2bf(p1 - bf2f(h1));
                #pragma unroll
                for (int db = 0; db < 4; ++db) O[qs][db][r] *= cc;
            }
        }

        short8v pfh[2], pfl[2];
        #pragma unroll
        for (int qs = 0; qs < 2; ++qs) {
            pfh[qs] = *(const short8v*)(PHw + (qs*16 + lc)*40 + lg*8);
            pfl[qs] = *(const short8v*)(PLw + (qs*16 + lc)*40 + lg*8);
        }

        #pragma unroll
        for (int db = 0; db < 4; ++db) {
            const size_t vo = vtbase + (size_t)(db*16 + lc) * TSEQ + k0 + lg*8;
            short8v vh = *(const short8v*)(vthi_ + vo);
            short8v vl = *(const short8v*)(vtlo_ + vo);
            #pragma unroll
            for (int qs = 0; qs < 2; ++qs) {
                O[qs][db] = MFMA16(pfh[qs], vh, O[qs][db]);
                O[qs][db] = MFMA16(pfh[qs], vl, O[qs][db]);
                O[qs][db] = MFMA16(pfl[qs], vh, O[qs][db]);
            }
        }
    }

    #pragma unroll
    for (int qs = 0; qs < 2; ++qs) {
        #pragma unroll
        for (int r = 0; r < 4; ++r) {
            const float inv = 1.f / lst[qs][r];
            const int trow = qbase + qs*16 + lg*4 + r;
            const size_t obase = ((size_t)(b * TSEQ + trow)) * EMB + h * HD;
            #pragma unroll
            for (int db = 0; db < 4; ++db) {
                const float val = O[qs][db][r] * inv;
                const u32 vh = f2bf(val);
                ohi[obase + db*16 + lc] = (u16)vh;
                olo[obase + db*16 + lc] = (u16)f2bf(val - bf2f(vh));
            }
            if (lc == 0) {
                m_out[bh * TSEQ + trow] = mst[qs][r];
                linv_out[bh * TSEQ + trow] = inv;
            }
        }
    }
}

// ---------------------------------------------------------------------------
// a_avg via MFMA score recompute + saved stats. Barrier-free, no LDS.
// ---------------------------------------------------------------------------
__global__ __launch_bounds__(256) void attn_avg_kernel(
    const u16* __restrict__ qhi_, const u16* __restrict__ qlo_,
    const u16* __restrict__ khi_, const u16* __restrict__ klo_,
    const float* __restrict__ pad, const float* __restrict__ m_arr,
    const float* __restrict__ linv_arr, float* __restrict__ a_avg)
{
    const int tid  = threadIdx.x;
    const int lane = tid & 63;
    const int w    = tid >> 6;
    const int b  = blockIdx.z;
    const int q0 = blockIdx.y << 5;
    const int k0 = blockIdx.x << 7;
    const int lg = lane >> 4, lc = lane & 15;
    const int kw = k0 + w * 32;

    const float pv0 = pad[b * TSEQ + kw + lc];
    const float pv1 = pad[b * TSEQ + kw + 16 + lc];

    f32x4 acc[2][2];
    #pragma unroll
    for (int qs = 0; qs < 2; ++qs)
        #pragma unroll
        for (int kb2 = 0; kb2 < 2; ++kb2) acc[qs][kb2] = (f32x4){0.f,0.f,0.f,0.f};

    for (int h = 0; h < NH; ++h) {
        const size_t hb = (size_t)(b * NH + h) * TSEQ;
        short8v qh[2][2], ql[2][2];
        #pragma unroll
        for (int qs = 0; qs < 2; ++qs) {
            const size_t qoff = (hb + q0 + qs*16 + lc) * HD + lg*8;
            #pragma unroll
            for (int s = 0; s < 2; ++s) {
                qh[qs][s] = *(const short8v*)(qhi_ + qoff + s*32);
                ql[qs][s] = *(const short8v*)(qlo_ + qoff + s*32);
            }
        }
        f32x4 S[2][2];
        #pragma unroll
        for (int qs = 0; qs < 2; ++qs)
            #pragma unroll
            for (int kb2 = 0; kb2 < 2; ++kb2) S[qs][kb2] = (f32x4){0.f,0.f,0.f,0.f};
        #pragma unroll
        for (int kb2 = 0; kb2 < 2; ++kb2) {
            #pragma unroll
            for (int s = 0; s < 2; ++s) {
                const size_t ko = (hb + kw + kb2*16 + lc) * HD + s*32 + lg*8;
                short8v kh = *(const short8v*)(khi_ + ko);
                short8v kl = *(const short8v*)(klo_ + ko);
                #pragma unroll
                for (int qs = 0; qs < 2; ++qs) {
                    S[qs][kb2] = MFMA16(qh[qs][s], kh, S[qs][kb2]);
                    S[qs][kb2] = MFMA16(qh[qs][s], kl, S[qs][kb2]);
                    S[qs][kb2] = MFMA16(ql[qs][s], kh, S[qs][kb2]);
                }
            }
        }
        #pragma unroll
        for (int qs = 0; qs < 2; ++qs) {
            #pragma unroll
            for (int r = 0; r < 4; ++r) {
                const size_t rix = hb + q0 + qs*16 + lg*4 + r;
                const float mh = m_arr[rix];
                const float li = linv_arr[rix];
                acc[qs][0][r] += EXP2((S[qs][0][r] + pv0 - mh) * L2E) * li;
                acc[qs][1][r] += EXP2((S[qs][1][r] + pv1 - mh) * L2E) * li;
            }
        }
    }

    const float invH = 1.0f / (float)NH;
    #pragma unroll
    for (int qs = 0; qs < 2; ++qs) {
        #pragma unroll
        for (int r = 0; r < 4; ++r) {
            const int row = q0 + qs*16 + lg*4 + r;
            #pragma unroll
            for (int kb2 = 0; kb2 < 2; ++kb2)
                a_avg[((size_t)b * TSEQ + row) * TSEQ + kw + kb2*16 + lc] =
                    acc[qs][kb2][r] * invH;
        }
    }
}

// ---------------------------------------------------------------------------
extern "C" void kernel_launch(void* const* d_in, const int* in_sizes, int n_in,
                              void* d_out, int out_size, void* d_ws, size_t ws_size,
                              hipStream_t stream)
{
    const float* x    = (const float*)d_in[0];
    const float* mre  = (const float*)d_in[1];
    const float* mim  = (const float*)d_in[2];
    const float* pad  = (const float*)d_in[3];
    const float* qkvw = (const float*)d_in[4];
    const float* qkvb = (const float*)d_in[5];
    const float* ow   = (const float*)d_in[6];
    const float* ob   = (const float*)d_in[7];

    float* out_o = (float*)d_out;                    // [B,T,E]
    float* out_a = out_o + (size_t)NB * TSEQ * EMB;  // [B,T,T]

    // o split-bf16 borrows the a_avg output region (16.8 MB of 32 MB);
    // consumed by mm_out before attn_avg overwrites it (stream-ordered).
    u16* ohi = (u16*)out_a;
    u16* olo = ohi + (size_t)NB * TSEQ * EMB;

    // ws (u16 units): q|k|v splits (6xSZ) + stats + x|w|ow splits  (~84.5 MB)
    const size_t SZ = (size_t)NB * NH * TSEQ * HD;   // 4194304
    u16* qhi  = (u16*)d_ws;
    u16* qlo  = qhi  + SZ;
    u16* khi  = qlo  + SZ;
    u16* klo  = khi  + SZ;
    u16* vthi = klo  + SZ;
    u16* vtlo = vthi + SZ;
    float* marr = (float*)(vtlo + SZ);
    float* linv = marr + (size_t)NB * NH * TSEQ;
    u16* xhi  = (u16*)(linv + (size_t)NB * NH * TSEQ);
    u16* xlo  = xhi + SZ;                            // x: 4096x1024
    u16* whi  = xlo + SZ;                            // qkv_w: 3072x1024
    u16* wlo  = whi + (size_t)3 * EMB * EMB;
    u16* owhi = wlo + (size_t)3 * EMB * EMB;         // o_w: 1024x1024
    u16* owlo = owhi + (size_t)EMB * EMB;

    // 0) split inputs to bf16 hi/lo
    conv_split_kernel<<<4096, 256, 0, stream>>>(x, xhi, xlo);      // 4.19M
    conv_split_kernel<<<3072, 256, 0, stream>>>(qkvw, whi, wlo);   // 3.15M
    conv_split_kernel<<<1024, 256, 0, stream>>>(ow, owhi, owlo);   // 1.05M

    // 1) QKV projection (MFMA) -> split q/k (BHTd) + v transposed (BHdT)
    mm_qkv_kernel<<<dim3(32, 24), 256, 0, stream>>>(
        xhi, xlo, whi, wlo, qkvb, qhi, qlo, khi, klo, vthi, vtlo);

    // 2) rotary on k (in place, split-bf16)
    rotary_k_kernel<<<8192, 256, 0, stream>>>(khi, klo, mre, mim);

    // 3) MFMA flash attention -> o split-bf16 + stats
    flash_attn_kernel<<<1024, 128, 0, stream>>>(
        qhi, qlo, khi, klo, vthi, vtlo, pad, ohi, olo, marr, linv);

    // 4) output projection (MFMA, consumes o-split)
    mm_out_kernel<<<dim3(32, 8), 256, 0, stream>>>(
        ohi, olo, owhi, owlo, ob, out_o);

    // 5) head-averaged probs -> a_avg (overwrites scratch region)
    attn_avg_kernel<<<dim3(16, 64, 2), 256, 0, stream>>>(
        qhi, qlo, khi, klo, pad, marr, linv, out_a);
}